// Round 2
// baseline (66.205 us; speedup 1.0000x reference)
//
#include <hip/hip_runtime.h>

// StablePolicy3phase: out[b,:] = sum_h softthresh(s[b]·W[h], bn[h]) + 0.001*s[b]
//   s   = clip(state-1.03,0,inf) - clip(0.97-state,0,inf)
//   W[h] = sum_k lambda[h,k]^2 * E_k  (symmetric 3x3, 6 unique elems)
//   bn  = 0.15 * clip(b,0) / sum(clip(b,0))     (global scalar sum)
//   softthresh(x,t) = copysign(max(|x|-t,0), x)
//
// Round-2 structure: per-head table lives in GLOBAL memory (d_ws), read at
// wave-uniform indices -> scalar-memory pipe (s_load), freeing the LDS pipe
// which round-1 analysis showed was the bottleneck (3x ds_read_b128/head
// x 8 waves/CU = 288 LDS cycles/head vs 84 VALU cycles/head).

#define VMAX_T 1.03f   // VMAX - 0.02
#define VMIN_T 0.97f   // VMIN + 0.02
#define SCALE_C 0.15f

// d_ws table layout: per head, 12 floats (48 B, 16B-aligned rows):
//   [0..3]  w00 w01 w02 w11
//   [4..7]  w12 w22 bn0 bn1
//   [8]     bn2   [9..11] pad

__global__ __launch_bounds__(256) void build_table_kernel(
    const float* __restrict__ bvec,
    const float* __restrict__ lam,
    float* __restrict__ tbl,
    int H)
{
    __shared__ float wsum[4];
    const int tid = threadIdx.x;

    float p = 0.f;
    if (tid < H) {
        p = fmaxf(bvec[tid * 3 + 0], 0.f)
          + fmaxf(bvec[tid * 3 + 1], 0.f)
          + fmaxf(bvec[tid * 3 + 2], 0.f);
    }
    #pragma unroll
    for (int off = 32; off > 0; off >>= 1)
        p += __shfl_down(p, off, 64);
    if ((tid & 63) == 0) wsum[tid >> 6] = p;
    __syncthreads();
    const float S = wsum[0] + wsum[1] + wsum[2] + wsum[3];
    const float inv = SCALE_C / S;

    if (tid < H) {
        float l0 = lam[tid * 6 + 0]; l0 *= l0;
        float l1 = lam[tid * 6 + 1]; l1 *= l1;
        float l2 = lam[tid * 6 + 2]; l2 *= l2;
        float l3 = lam[tid * 6 + 3]; l3 *= l3;
        float l4 = lam[tid * 6 + 4]; l4 *= l4;
        float l5 = lam[tid * 6 + 5]; l5 *= l5;
        // E order: (0,0),(1,0),(1,1),(2,0),(2,1),(2,2)
        const float w00 = l0 + l1 + l3;
        const float w11 = l1 + l2 + l4;
        const float w22 = l3 + l4 + l5;
        const float w01 = -l1;
        const float w02 = -l3;
        const float w12 = -l4;
        const float bn0 = fmaxf(bvec[tid * 3 + 0], 0.f) * inv;
        const float bn1 = fmaxf(bvec[tid * 3 + 1], 0.f) * inv;
        const float bn2 = fmaxf(bvec[tid * 3 + 2], 0.f) * inv;
        float4* row = (float4*)(tbl + tid * 12);
        row[0] = make_float4(w00, w01, w02, w11);
        row[1] = make_float4(w12, w22, bn0, bn1);
        row[2] = make_float4(bn2, 0.f, 0.f, 0.f);
    }
}

__global__ __launch_bounds__(256) void policy_main_kernel(
    const float* __restrict__ state,
    const float* __restrict__ tbl,
    float* __restrict__ out,
    int B, int H)
{
    const int r = blockIdx.x * blockDim.x + threadIdx.x;
    if (r >= B) return;

    const float x0 = state[r * 3 + 0];
    const float x1 = state[r * 3 + 1];
    const float x2 = state[r * 3 + 2];
    const float s0 = fmaxf(x0 - VMAX_T, 0.f) - fmaxf(VMIN_T - x0, 0.f);
    const float s1 = fmaxf(x1 - VMAX_T, 0.f) - fmaxf(VMIN_T - x1, 0.f);
    const float s2 = fmaxf(x2 - VMAX_T, 0.f) - fmaxf(VMIN_T - x2, 0.f);

    float a0 = 0.f, a1 = 0.f, a2 = 0.f;

    #pragma unroll 4
    for (int h = 0; h < H; ++h) {
        // wave-uniform indices into read-only restrict global -> scalar loads
        const float4 wa = *(const float4*)(tbl + h * 12 + 0);  // w00 w01 w02 w11
        const float4 wb = *(const float4*)(tbl + h * 12 + 4);  // w12 w22 bn0 bn1
        const float  bn2 = tbl[h * 12 + 8];

        const float v0 = s0 * wa.x + s1 * wa.y + s2 * wa.z;
        const float v1 = s0 * wa.y + s1 * wa.w + s2 * wb.x;
        const float v2 = s0 * wa.z + s1 * wb.x + s2 * wb.y;

        const float d0 = fmaxf(fabsf(v0) - wb.z, 0.f);
        const float d1 = fmaxf(fabsf(v1) - wb.w, 0.f);
        const float d2 = fmaxf(fabsf(v2) - bn2, 0.f);

        a0 += copysignf(d0, v0);
        a1 += copysignf(d1, v1);
        a2 += copysignf(d2, v2);
    }

    out[r * 3 + 0] = a0 + 0.001f * s0;
    out[r * 3 + 1] = a1 + 0.001f * s1;
    out[r * 3 + 2] = a2 + 0.001f * s2;
}

extern "C" void kernel_launch(void* const* d_in, const int* in_sizes, int n_in,
                              void* d_out, int out_size, void* d_ws, size_t ws_size,
                              hipStream_t stream) {
    const float* state = (const float*)d_in[0];
    const float* bvec  = (const float*)d_in[1];
    const float* lam   = (const float*)d_in[2];
    float* out = (float*)d_out;
    float* tbl = (float*)d_ws;   // 256 heads * 12 floats = 12 KB

    const int B = in_sizes[0] / 3;
    const int H = in_sizes[1] / 3;   // 256

    hipLaunchKernelGGL(build_table_kernel, dim3(1), dim3(256), 0, stream,
                       bvec, lam, tbl, H);

    const int block = 256;
    const int grid = (B + block - 1) / block;
    hipLaunchKernelGGL(policy_main_kernel, dim3(grid), dim3(block), 0, stream,
                       state, tbl, out, B, H);
}

// Round 3
// 33.411 us; speedup vs baseline: 1.9815x; 1.9815x over previous
//
#include <hip/hip_runtime.h>

// StablePolicy3phase: out[b,:] = sum_h softthresh(s[b]·W[h], bn[h]) + 0.001*s[b]
//   s   = clip(state-1.03,0,inf) - clip(0.97-state,0,inf)
//   W[h] = sum_k lambda[h,k]^2 * E_k  (symmetric 3x3, 6 unique elems)
//   bn  = 0.15 * clip(b,0) / sum(clip(b,0))     (global scalar sum)
//   softthresh(x,t) = copysign(max(|x|-t,0), x)
//
// Round-3: table in global (d_ws), read via SCALAR loads in 8-head groups.
// Round-2 failed (59us, VALUBusy 22%) because SMEM is out-of-order -> every
// use forces lgkmcnt(0) full drain; compiler drained per-head (~42 issue-cyc
// compute vs ~270-cyc stall). Fix: stage 72 contiguous dwords (8 heads) into
// an unrolled local array per iteration -> one drain per 336 SIMD-cycles of
// compute; 2 waves/SIMD cover the residual stall.

#define VMAX_T 1.03f   // VMAX - 0.02
#define VMIN_T 0.97f   // VMIN + 0.02
#define SCALE_C 0.15f

// tbl layout: [H][9] floats, packed 36B rows:
//   w00 w01 w02 w11 w12 w22 bn0 bn1 bn2

__global__ __launch_bounds__(256) void build_table_kernel(
    const float* __restrict__ bvec,
    const float* __restrict__ lam,
    float* __restrict__ tbl,
    int H)
{
    __shared__ float wsum[4];
    const int tid = threadIdx.x;

    float p = 0.f;
    if (tid < H) {
        p = fmaxf(bvec[tid * 3 + 0], 0.f)
          + fmaxf(bvec[tid * 3 + 1], 0.f)
          + fmaxf(bvec[tid * 3 + 2], 0.f);
    }
    #pragma unroll
    for (int off = 32; off > 0; off >>= 1)
        p += __shfl_down(p, off, 64);
    if ((tid & 63) == 0) wsum[tid >> 6] = p;
    __syncthreads();
    const float S = wsum[0] + wsum[1] + wsum[2] + wsum[3];
    const float inv = SCALE_C / S;

    if (tid < H) {
        float l0 = lam[tid * 6 + 0]; l0 *= l0;
        float l1 = lam[tid * 6 + 1]; l1 *= l1;
        float l2 = lam[tid * 6 + 2]; l2 *= l2;
        float l3 = lam[tid * 6 + 3]; l3 *= l3;
        float l4 = lam[tid * 6 + 4]; l4 *= l4;
        float l5 = lam[tid * 6 + 5]; l5 *= l5;
        // E order: (0,0),(1,0),(1,1),(2,0),(2,1),(2,2)
        float* row = tbl + tid * 9;
        row[0] = l0 + l1 + l3;   // w00
        row[1] = -l1;            // w01
        row[2] = -l3;            // w02
        row[3] = l1 + l2 + l4;   // w11
        row[4] = -l4;            // w12
        row[5] = l3 + l4 + l5;   // w22
        row[6] = fmaxf(bvec[tid * 3 + 0], 0.f) * inv;  // bn0
        row[7] = fmaxf(bvec[tid * 3 + 1], 0.f) * inv;  // bn1
        row[8] = fmaxf(bvec[tid * 3 + 2], 0.f) * inv;  // bn2
    }
}

__global__ __launch_bounds__(256) void policy_main_kernel(
    const float* __restrict__ state,
    const float* __restrict__ tbl,
    float* __restrict__ out,
    int B)
{
    const int r = blockIdx.x * blockDim.x + threadIdx.x;
    if (r >= B) return;

    const float x0 = state[r * 3 + 0];
    const float x1 = state[r * 3 + 1];
    const float x2 = state[r * 3 + 2];
    const float s0 = fmaxf(x0 - VMAX_T, 0.f) - fmaxf(VMIN_T - x0, 0.f);
    const float s1 = fmaxf(x1 - VMAX_T, 0.f) - fmaxf(VMIN_T - x1, 0.f);
    const float s2 = fmaxf(x2 - VMAX_T, 0.f) - fmaxf(VMIN_T - x2, 0.f);

    float a0 = 0.f, a1 = 0.f, a2 = 0.f;

    // 256 heads = 32 groups of 8 heads (72 contiguous dwords each)
    for (int grp = 0; grp < 32; ++grp) {
        float g[72];
        const int gbase = grp * 72;   // uniform -> scalar loads
        #pragma unroll
        for (int k = 0; k < 72; ++k)
            g[k] = tbl[gbase + k];

        // Pin stage boundary: no interleaving of loads into compute
        __builtin_amdgcn_sched_barrier(0);

        #pragma unroll
        for (int hh = 0; hh < 8; ++hh) {
            const float w00 = g[hh * 9 + 0];
            const float w01 = g[hh * 9 + 1];
            const float w02 = g[hh * 9 + 2];
            const float w11 = g[hh * 9 + 3];
            const float w12 = g[hh * 9 + 4];
            const float w22 = g[hh * 9 + 5];
            const float bn0 = g[hh * 9 + 6];
            const float bn1 = g[hh * 9 + 7];
            const float bn2 = g[hh * 9 + 8];

            const float v0 = fmaf(s2, w02, fmaf(s1, w01, s0 * w00));
            const float v1 = fmaf(s2, w12, fmaf(s1, w11, s0 * w01));
            const float v2 = fmaf(s2, w22, fmaf(s1, w12, s0 * w02));

            const float d0 = fmaxf(fabsf(v0) - bn0, 0.f);
            const float d1 = fmaxf(fabsf(v1) - bn1, 0.f);
            const float d2 = fmaxf(fabsf(v2) - bn2, 0.f);

            a0 += copysignf(d0, v0);
            a1 += copysignf(d1, v1);
            a2 += copysignf(d2, v2);
        }

        __builtin_amdgcn_sched_barrier(0);
    }

    out[r * 3 + 0] = fmaf(0.001f, s0, a0);
    out[r * 3 + 1] = fmaf(0.001f, s1, a1);
    out[r * 3 + 2] = fmaf(0.001f, s2, a2);
}

extern "C" void kernel_launch(void* const* d_in, const int* in_sizes, int n_in,
                              void* d_out, int out_size, void* d_ws, size_t ws_size,
                              hipStream_t stream) {
    const float* state = (const float*)d_in[0];
    const float* bvec  = (const float*)d_in[1];
    const float* lam   = (const float*)d_in[2];
    float* out = (float*)d_out;
    float* tbl = (float*)d_ws;   // 256 heads * 9 floats = 9216 B

    const int B = in_sizes[0] / 3;
    const int H = in_sizes[1] / 3;   // 256

    hipLaunchKernelGGL(build_table_kernel, dim3(1), dim3(256), 0, stream,
                       bvec, lam, tbl, H);

    const int block = 256;
    const int grid = (B + block - 1) / block;
    hipLaunchKernelGGL(policy_main_kernel, dim3(grid), dim3(block), 0, stream,
                       state, tbl, out, B);
}

// Round 4
// 29.696 us; speedup vs baseline: 2.2294x; 1.1251x over previous
//
#include <hip/hip_runtime.h>

// StablePolicy3phase fused kernel (round 4).
//   out[b,:] = sum_h softthresh(s[b]·W[h], bn[h]) + 0.001*s[b]
//   softthresh(x,t) = copysign(max(|x|-t,0), x)
//
// Structure: LDS broadcast table, 32 B/head (2 x ds_read_b128):
//   tA[h] = {w00, w01, w02, w11}                        (f32)
//   tB[h] = {w12, w22, pack(bn0_lo|bn1_hi), bn2_hi}     (bn as bf16 bits)
// R=2 rows/thread, grid=256 blocks: per-CU LDS = 4 waves*2*12 = 96 cyc/head,
// VALU/SIMD = 88 cyc/head -> balanced ~10 us main loop (round-1 was 288 LDS
// cyc/head -> 28.8 us, LDS-pipe-bound).

#define VMAX_T 1.03f   // VMAX - 0.02
#define VMIN_T 0.97f   // VMIN + 0.02
#define SCALE_C 0.15f

__device__ inline unsigned bf16hi_rne(float x) {
    unsigned u = __float_as_uint(x);
    return (u + 0x7FFFu + ((u >> 16) & 1u)) & 0xFFFF0000u;  // RNE, keep high half
}

__global__ __launch_bounds__(256) void policy_fused_kernel(
    const float* __restrict__ state,
    const float* __restrict__ bvec,
    const float* __restrict__ lam,
    float* __restrict__ out,
    int B)
{
    __shared__ float4 tA[256];
    __shared__ float4 tB[256];
    __shared__ float wsum[4];

    const int tid = threadIdx.x;

    // ---- Prologue: global sum S = sum clip(b,0) (block-redundant) ----
    const float b0 = fmaxf(bvec[tid * 3 + 0], 0.f);
    const float b1 = fmaxf(bvec[tid * 3 + 1], 0.f);
    const float b2 = fmaxf(bvec[tid * 3 + 2], 0.f);
    float p = b0 + b1 + b2;
    #pragma unroll
    for (int off = 32; off > 0; off >>= 1)
        p += __shfl_down(p, off, 64);
    if ((tid & 63) == 0) wsum[tid >> 6] = p;
    __syncthreads();
    const float S = wsum[0] + wsum[1] + wsum[2] + wsum[3];
    const float inv = SCALE_C / S;

    // ---- Build head `tid`'s packed 32B row ----
    {
        float l0 = lam[tid * 6 + 0]; l0 *= l0;
        float l1 = lam[tid * 6 + 1]; l1 *= l1;
        float l2 = lam[tid * 6 + 2]; l2 *= l2;
        float l3 = lam[tid * 6 + 3]; l3 *= l3;
        float l4 = lam[tid * 6 + 4]; l4 *= l4;
        float l5 = lam[tid * 6 + 5]; l5 *= l5;
        // E order: (0,0),(1,0),(1,1),(2,0),(2,1),(2,2)
        const float w00 = l0 + l1 + l3;
        const float w11 = l1 + l2 + l4;
        const float w22 = l3 + l4 + l5;
        const unsigned hb0 = bf16hi_rne(b0 * inv);
        const unsigned hb1 = bf16hi_rne(b1 * inv);
        const unsigned hb2 = bf16hi_rne(b2 * inv);
        tA[tid] = make_float4(w00, -l1, -l3, w11);
        tB[tid] = make_float4(-l4, w22,
                              __uint_as_float((hb0 >> 16) | hb1),
                              __uint_as_float(hb2));
    }
    __syncthreads();

    // ---- Main: 2 rows per thread ----
    const int r0 = blockIdx.x * 512 + tid;
    const int r1 = r0 + 256;
    const bool ok0 = (r0 < B);
    const bool ok1 = (r1 < B);

    float x0a = 0.f, x1a = 0.f, x2a = 0.f, x0b = 0.f, x1b = 0.f, x2b = 0.f;
    if (ok0) { x0a = state[r0*3+0]; x1a = state[r0*3+1]; x2a = state[r0*3+2]; }
    if (ok1) { x0b = state[r1*3+0]; x1b = state[r1*3+1]; x2b = state[r1*3+2]; }

    const float s0a = fmaxf(x0a - VMAX_T, 0.f) - fmaxf(VMIN_T - x0a, 0.f);
    const float s1a = fmaxf(x1a - VMAX_T, 0.f) - fmaxf(VMIN_T - x1a, 0.f);
    const float s2a = fmaxf(x2a - VMAX_T, 0.f) - fmaxf(VMIN_T - x2a, 0.f);
    const float s0b = fmaxf(x0b - VMAX_T, 0.f) - fmaxf(VMIN_T - x0b, 0.f);
    const float s1b = fmaxf(x1b - VMAX_T, 0.f) - fmaxf(VMIN_T - x1b, 0.f);
    const float s2b = fmaxf(x2b - VMAX_T, 0.f) - fmaxf(VMIN_T - x2b, 0.f);

    float a0a = 0.f, a1a = 0.f, a2a = 0.f;
    float a0b = 0.f, a1b = 0.f, a2b = 0.f;

    #pragma unroll 4
    for (int h = 0; h < 256; ++h) {
        const float4 wa = tA[h];   // w00 w01 w02 w11   (uniform -> broadcast)
        const float4 wb = tB[h];   // w12 w22 bn01 bn2

        const unsigned pk = __float_as_uint(wb.z);
        const float bn0 = __uint_as_float(pk << 16);
        const float bn1 = __uint_as_float(pk & 0xFFFF0000u);
        const float bn2 = wb.w;

        const float v0a = fmaf(s2a, wa.z, fmaf(s1a, wa.y, s0a * wa.x));
        const float v1a = fmaf(s2a, wb.x, fmaf(s1a, wa.w, s0a * wa.y));
        const float v2a = fmaf(s2a, wb.y, fmaf(s1a, wb.x, s0a * wa.z));
        const float v0b = fmaf(s2b, wa.z, fmaf(s1b, wa.y, s0b * wa.x));
        const float v1b = fmaf(s2b, wb.x, fmaf(s1b, wa.w, s0b * wa.y));
        const float v2b = fmaf(s2b, wb.y, fmaf(s1b, wb.x, s0b * wa.z));

        const float d0a = fmaxf(fabsf(v0a) - bn0, 0.f);
        const float d1a = fmaxf(fabsf(v1a) - bn1, 0.f);
        const float d2a = fmaxf(fabsf(v2a) - bn2, 0.f);
        const float d0b = fmaxf(fabsf(v0b) - bn0, 0.f);
        const float d1b = fmaxf(fabsf(v1b) - bn1, 0.f);
        const float d2b = fmaxf(fabsf(v2b) - bn2, 0.f);

        a0a += copysignf(d0a, v0a);
        a1a += copysignf(d1a, v1a);
        a2a += copysignf(d2a, v2a);
        a0b += copysignf(d0b, v0b);
        a1b += copysignf(d1b, v1b);
        a2b += copysignf(d2b, v2b);
    }

    if (ok0) {
        out[r0*3+0] = fmaf(0.001f, s0a, a0a);
        out[r0*3+1] = fmaf(0.001f, s1a, a1a);
        out[r0*3+2] = fmaf(0.001f, s2a, a2a);
    }
    if (ok1) {
        out[r1*3+0] = fmaf(0.001f, s0b, a0b);
        out[r1*3+1] = fmaf(0.001f, s1b, a1b);
        out[r1*3+2] = fmaf(0.001f, s2b, a2b);
    }
}

extern "C" void kernel_launch(void* const* d_in, const int* in_sizes, int n_in,
                              void* d_out, int out_size, void* d_ws, size_t ws_size,
                              hipStream_t stream) {
    const float* state = (const float*)d_in[0];
    const float* bvec  = (const float*)d_in[1];
    const float* lam   = (const float*)d_in[2];
    float* out = (float*)d_out;

    const int B = in_sizes[0] / 3;   // 131072

    const int grid = (B + 511) / 512;   // 2 rows/thread, 256 threads
    hipLaunchKernelGGL(policy_fused_kernel, dim3(grid), dim3(256), 0, stream,
                       state, bvec, lam, out, B);
}

// Round 5
// 29.356 us; speedup vs baseline: 2.2552x; 1.0116x over previous
//
#include <hip/hip_runtime.h>

// StablePolicy3phase fused kernel (round 5).
//   out[b,:] = sum_h softthresh(s[b]·W[h], bn[h]) + 0.001*s[b]
//   softthresh(x,t) = x - med3(x, -t, t)        (exact-FP clamp identity)
//
// Rounds 1/4 showed the head loop is bound by LDS (throughput at 2 waves/SIMD,
// latency at 1 wave/SIMD). Round 5 removes ALL memory ops from the main loop:
// the 256x9 f32 table lives in wave-distributed VGPRs (lane l holds heads
// 4l..4l+3 = 36 VGPRs); per head, 9 v_readlane broadcasts (pure VALU->SGPR)
// feed the math. R=2 rows/thread amortizes the readlanes. 180 VALU instr per
// 4-head group -> 23.0k SIMD-cyc ≈ 9.6 us issue-bound floor.

#define VMAX_T 1.03f   // VMAX - 0.02
#define VMIN_T 0.97f   // VMIN + 0.02
#define SCALE_C 0.15f

__device__ __forceinline__ float rdlane(float v, int lane) {
    return __uint_as_float((unsigned)__builtin_amdgcn_readlane((int)__float_as_uint(v), lane));
}

__global__ __launch_bounds__(256) void policy_kernel(
    const float* __restrict__ state,
    const float* __restrict__ bvec,
    const float* __restrict__ lam,
    float* __restrict__ out,
    int B)
{
    __shared__ float tbl[256 * 12];   // head-major, stride 12 for float4 align
    __shared__ float wsum[4];
    const int tid = threadIdx.x;

    // ---- Prologue: S = sum clip(b,0); build head tid's 9-float row ----
    const float b0 = fmaxf(bvec[tid * 3 + 0], 0.f);
    const float b1 = fmaxf(bvec[tid * 3 + 1], 0.f);
    const float b2 = fmaxf(bvec[tid * 3 + 2], 0.f);
    float p = b0 + b1 + b2;
    #pragma unroll
    for (int off = 32; off > 0; off >>= 1)
        p += __shfl_down(p, off, 64);
    if ((tid & 63) == 0) wsum[tid >> 6] = p;
    __syncthreads();
    const float S = wsum[0] + wsum[1] + wsum[2] + wsum[3];
    const float inv = SCALE_C / S;

    {
        float l0 = lam[tid * 6 + 0]; l0 *= l0;
        float l1 = lam[tid * 6 + 1]; l1 *= l1;
        float l2 = lam[tid * 6 + 2]; l2 *= l2;
        float l3 = lam[tid * 6 + 3]; l3 *= l3;
        float l4 = lam[tid * 6 + 4]; l4 *= l4;
        float l5 = lam[tid * 6 + 5]; l5 *= l5;
        // E order: (0,0),(1,0),(1,1),(2,0),(2,1),(2,2)
        float* row = &tbl[tid * 12];
        row[0] = l0 + l1 + l3;   // w00
        row[1] = -l1;            // w01
        row[2] = -l3;            // w02
        row[3] = l1 + l2 + l4;   // w11
        row[4] = -l4;            // w12
        row[5] = l3 + l4 + l5;   // w22
        row[6] = b0 * inv;       // bn0
        row[7] = b1 * inv;       // bn1
        row[8] = b2 * inv;       // bn2
        row[9] = 0.f; row[10] = 0.f; row[11] = 0.f;
    }
    __syncthreads();

    // ---- Distribute table into wave VGPRs: lane l holds heads 4l..4l+3 ----
    const int lane = tid & 63;
    float t[36];
    #pragma unroll
    for (int s = 0; s < 4; ++s) {
        const float4 q0 = *(const float4*)&tbl[(4 * lane + s) * 12 + 0];
        const float4 q1 = *(const float4*)&tbl[(4 * lane + s) * 12 + 4];
        const float  q2 = tbl[(4 * lane + s) * 12 + 8];
        t[s * 9 + 0] = q0.x; t[s * 9 + 1] = q0.y; t[s * 9 + 2] = q0.z;
        t[s * 9 + 3] = q0.w; t[s * 9 + 4] = q1.x; t[s * 9 + 5] = q1.y;
        t[s * 9 + 6] = q1.z; t[s * 9 + 7] = q1.w; t[s * 9 + 8] = q2;
    }

    // ---- Two rows per thread ----
    const int r0 = blockIdx.x * 512 + tid;
    const int r1 = r0 + 256;
    const bool ok0 = (r0 < B);
    const bool ok1 = (r1 < B);

    float x0a = 0.f, x1a = 0.f, x2a = 0.f, x0b = 0.f, x1b = 0.f, x2b = 0.f;
    if (ok0) { x0a = state[r0*3+0]; x1a = state[r0*3+1]; x2a = state[r0*3+2]; }
    if (ok1) { x0b = state[r1*3+0]; x1b = state[r1*3+1]; x2b = state[r1*3+2]; }

    const float s0a = fmaxf(x0a - VMAX_T, 0.f) - fmaxf(VMIN_T - x0a, 0.f);
    const float s1a = fmaxf(x1a - VMAX_T, 0.f) - fmaxf(VMIN_T - x1a, 0.f);
    const float s2a = fmaxf(x2a - VMAX_T, 0.f) - fmaxf(VMIN_T - x2a, 0.f);
    const float s0b = fmaxf(x0b - VMAX_T, 0.f) - fmaxf(VMIN_T - x0b, 0.f);
    const float s1b = fmaxf(x1b - VMAX_T, 0.f) - fmaxf(VMIN_T - x1b, 0.f);
    const float s2b = fmaxf(x2b - VMAX_T, 0.f) - fmaxf(VMIN_T - x2b, 0.f);

    float a0a = 0.f, a1a = 0.f, a2a = 0.f;
    float a0b = 0.f, a1b = 0.f, a2b = 0.f;

    for (int g = 0; g < 64; ++g) {
        #pragma unroll
        for (int s = 0; s < 4; ++s) {
            const float w00 = rdlane(t[s * 9 + 0], g);
            const float w01 = rdlane(t[s * 9 + 1], g);
            const float w02 = rdlane(t[s * 9 + 2], g);
            const float w11 = rdlane(t[s * 9 + 3], g);
            const float w12 = rdlane(t[s * 9 + 4], g);
            const float w22 = rdlane(t[s * 9 + 5], g);
            const float bn0 = rdlane(t[s * 9 + 6], g);
            const float bn1 = rdlane(t[s * 9 + 7], g);
            const float bn2 = rdlane(t[s * 9 + 8], g);

            float v;
            v = fmaf(s2a, w02, fmaf(s1a, w01, s0a * w00));
            a0a += v - __builtin_amdgcn_fmed3f(v, -bn0, bn0);
            v = fmaf(s2a, w12, fmaf(s1a, w11, s0a * w01));
            a1a += v - __builtin_amdgcn_fmed3f(v, -bn1, bn1);
            v = fmaf(s2a, w22, fmaf(s1a, w12, s0a * w02));
            a2a += v - __builtin_amdgcn_fmed3f(v, -bn2, bn2);

            v = fmaf(s2b, w02, fmaf(s1b, w01, s0b * w00));
            a0b += v - __builtin_amdgcn_fmed3f(v, -bn0, bn0);
            v = fmaf(s2b, w12, fmaf(s1b, w11, s0b * w01));
            a1b += v - __builtin_amdgcn_fmed3f(v, -bn1, bn1);
            v = fmaf(s2b, w22, fmaf(s1b, w12, s0b * w02));
            a2b += v - __builtin_amdgcn_fmed3f(v, -bn2, bn2);
        }
    }

    if (ok0) {
        out[r0*3+0] = fmaf(0.001f, s0a, a0a);
        out[r0*3+1] = fmaf(0.001f, s1a, a1a);
        out[r0*3+2] = fmaf(0.001f, s2a, a2a);
    }
    if (ok1) {
        out[r1*3+0] = fmaf(0.001f, s0b, a0b);
        out[r1*3+1] = fmaf(0.001f, s1b, a1b);
        out[r1*3+2] = fmaf(0.001f, s2b, a2b);
    }
}

extern "C" void kernel_launch(void* const* d_in, const int* in_sizes, int n_in,
                              void* d_out, int out_size, void* d_ws, size_t ws_size,
                              hipStream_t stream) {
    const float* state = (const float*)d_in[0];
    const float* bvec  = (const float*)d_in[1];
    const float* lam   = (const float*)d_in[2];
    float* out = (float*)d_out;

    const int B = in_sizes[0] / 3;   // 131072

    const int grid = (B + 511) / 512;   // 2 rows/thread, 256 threads/block
    hipLaunchKernelGGL(policy_kernel, dim3(grid), dim3(256), 0, stream,
                       state, bvec, lam, out, B);
}

// Round 6
// 23.987 us; speedup vs baseline: 2.7600x; 1.2238x over previous
//
#include <hip/hip_runtime.h>

// StablePolicy3phase fused kernel (round 6).
//   out[b,:] = sum_h softthresh(s[b]·W[h], bn[h]) + 0.001*s[b]
//   softthresh(x,t) = x - med3(x, -t, t)
//
// Rounds 4/5 (1 wave/SIMD) stuck at ~29us = ~33% issue efficiency: with a
// single resident wave, FMA latency + readlane->SGPR hazards are fully
// exposed. Round 6 splits heads 8-ways to restore TLP: 512-thread blocks
// (8 waves), wave q owns head chunk q (32 heads), each thread does 4 rows x
// 32 heads in pure register math (9 readlane + 72 VALU per head); partials
// combined through LDS once at the end. 4096 waves = 4 waves/SIMD.
// Dense-issue floor ~8.6us.

#define VMAX_T 1.03f   // VMAX - 0.02
#define VMIN_T 0.97f   // VMIN + 0.02
#define SCALE_C 0.15f

__device__ __forceinline__ float rdlane(float v, int lane) {
    return __uint_as_float((unsigned)__builtin_amdgcn_readlane((int)__float_as_uint(v), lane));
}

__device__ __forceinline__ float softacc(float v, float t) {
    // x - clamp(x, -t, t); exact-FP equal to relu(x-t)-relu(-x-t)
    return v - __builtin_amdgcn_fmed3f(v, -t, t);
}

__global__ __launch_bounds__(512) void policy_kernel(
    const float* __restrict__ state,
    const float* __restrict__ bvec,
    const float* __restrict__ lam,
    float* __restrict__ out,
    int B)
{
    __shared__ float part[7][64][12];   // 21.5 KB: partials from waves 1..7
    __shared__ float wsum[8];

    const int tid  = threadIdx.x;
    const int lane = tid & 63;
    const int q    = tid >> 6;                // wave id = head chunk 0..7
    const int head = (q << 5) | (lane & 31);  // this lane's owned head

    // ---- per-head b clips; block-wide sum over the 256 distinct heads ----
    const float hb0 = fmaxf(bvec[head * 3 + 0], 0.f);
    const float hb1 = fmaxf(bvec[head * 3 + 1], 0.f);
    const float hb2 = fmaxf(bvec[head * 3 + 2], 0.f);

    float p = (lane < 32) ? (hb0 + hb1 + hb2) : 0.f;   // lanes>=32 duplicate heads
    #pragma unroll
    for (int off = 32; off > 0; off >>= 1)
        p += __shfl_down(p, off, 64);
    if (lane == 0) wsum[q] = p;
    __syncthreads();
    const float S = wsum[0] + wsum[1] + wsum[2] + wsum[3]
                  + wsum[4] + wsum[5] + wsum[6] + wsum[7];
    const float inv = SCALE_C / S;

    // ---- this lane's head parameters (private VGPRs; readlane source) ----
    const float2 lm0 = *(const float2*)&lam[head * 6 + 0];
    const float2 lm1 = *(const float2*)&lam[head * 6 + 2];
    const float2 lm2 = *(const float2*)&lam[head * 6 + 4];
    const float l0 = lm0.x * lm0.x;
    const float l1 = lm0.y * lm0.y;
    const float l2 = lm1.x * lm1.x;
    const float l3 = lm1.y * lm1.y;
    const float l4 = lm2.x * lm2.x;
    const float l5 = lm2.y * lm2.y;
    // E order: (0,0),(1,0),(1,1),(2,0),(2,1),(2,2)
    const float t0 = l0 + l1 + l3;   // w00
    const float t1 = -l1;            // w01
    const float t2 = -l3;            // w02
    const float t3 = l1 + l2 + l4;   // w11
    const float t4 = -l4;            // w12
    const float t5 = l3 + l4 + l5;   // w22
    const float t6 = hb0 * inv;      // bn0
    const float t7 = hb1 * inv;      // bn1
    const float t8 = hb2 * inv;      // bn2

    // ---- 4 rows per thread: rbase, +64, +128, +192 ----
    const int rbase = blockIdx.x * 256 + lane;

    float s[4][3];
    #pragma unroll
    for (int k = 0; k < 4; ++k) {
        const int r = rbase + 64 * k;
        float x0 = 0.f, x1 = 0.f, x2 = 0.f;
        if (r < B) { x0 = state[r*3+0]; x1 = state[r*3+1]; x2 = state[r*3+2]; }
        s[k][0] = fmaxf(x0 - VMAX_T, 0.f) - fmaxf(VMIN_T - x0, 0.f);
        s[k][1] = fmaxf(x1 - VMAX_T, 0.f) - fmaxf(VMIN_T - x1, 0.f);
        s[k][2] = fmaxf(x2 - VMAX_T, 0.f) - fmaxf(VMIN_T - x2, 0.f);
    }

    float acc[4][3] = {{0.f,0.f,0.f},{0.f,0.f,0.f},{0.f,0.f,0.f},{0.f,0.f,0.f}};

    // ---- main loop: 32 heads, pure register math ----
    #pragma unroll 2
    for (int g = 0; g < 32; ++g) {
        const float w00 = rdlane(t0, g);
        const float w01 = rdlane(t1, g);
        const float w02 = rdlane(t2, g);
        const float w11 = rdlane(t3, g);
        const float w12 = rdlane(t4, g);
        const float w22 = rdlane(t5, g);
        const float bn0 = rdlane(t6, g);
        const float bn1 = rdlane(t7, g);
        const float bn2 = rdlane(t8, g);

        #pragma unroll
        for (int k = 0; k < 4; ++k) {
            const float v0 = fmaf(s[k][2], w02, fmaf(s[k][1], w01, s[k][0] * w00));
            const float v1 = fmaf(s[k][2], w12, fmaf(s[k][1], w11, s[k][0] * w01));
            const float v2 = fmaf(s[k][2], w22, fmaf(s[k][1], w12, s[k][0] * w02));
            acc[k][0] += softacc(v0, bn0);
            acc[k][1] += softacc(v1, bn1);
            acc[k][2] += softacc(v2, bn2);
        }
    }

    // ---- combine the 8 head-chunk partials through LDS ----
    if (q != 0) {
        float* dst = &part[q - 1][lane][0];
        #pragma unroll
        for (int k = 0; k < 4; ++k) {
            dst[k*3+0] = acc[k][0];
            dst[k*3+1] = acc[k][1];
            dst[k*3+2] = acc[k][2];
        }
    }
    __syncthreads();

    if (q == 0) {
        #pragma unroll
        for (int k = 0; k < 4; ++k) {
            float a0 = acc[k][0], a1 = acc[k][1], a2 = acc[k][2];
            #pragma unroll
            for (int w = 0; w < 7; ++w) {
                a0 += part[w][lane][k*3+0];
                a1 += part[w][lane][k*3+1];
                a2 += part[w][lane][k*3+2];
            }
            const int r = rbase + 64 * k;
            if (r < B) {
                out[r*3+0] = fmaf(0.001f, s[k][0], a0);
                out[r*3+1] = fmaf(0.001f, s[k][1], a1);
                out[r*3+2] = fmaf(0.001f, s[k][2], a2);
            }
        }
    }
}

extern "C" void kernel_launch(void* const* d_in, const int* in_sizes, int n_in,
                              void* d_out, int out_size, void* d_ws, size_t ws_size,
                              hipStream_t stream) {
    const float* state = (const float*)d_in[0];
    const float* bvec  = (const float*)d_in[1];
    const float* lam   = (const float*)d_in[2];
    float* out = (float*)d_out;

    const int B = in_sizes[0] / 3;   // 131072

    const int grid = (B + 255) / 256;   // 256 rows per 512-thread block
    hipLaunchKernelGGL(policy_kernel, dim3(grid), dim3(512), 0, stream,
                       state, bvec, lam, out, B);
}